// Round 1
// baseline (3492.549 us; speedup 1.0000x reference)
//
#include <hip/hip_runtime.h>
#include <math.h>

#define H 256
#define D 300
#define NE 37
#define NLEAF 65536
#define NTOT 87381
#define NINT 21845      // internal nodes
#define NICH 87380      // 4*NINT = total internal children
#define PERMPAD 1184    // 37*32 worst-case padding per level

__device__ const int g_offs[10] = {0,65536,81920,86016,87040,87296,87360,87376,87380,87381};
static const int h_offs[10]     = {0,65536,81920,86016,87040,87296,87360,87376,87380,87381};

__device__ __forceinline__ float sigm(float v){ return 1.0f/(1.0f+__expf(-v)); }

// ---------------- weight transposes (once per launch, ~3M elems) --------------
__global__ void k_transpose(const float* __restrict__ ioux_w, const float* __restrict__ fx_w,
                            const float* __restrict__ iouh_w, const float* __restrict__ fh_w,
                            const float* __restrict__ e2h_w,
                            float* __restrict__ xwT, float* __restrict__ iouhT,
                            float* __restrict__ fhT, float* __restrict__ e2hT)
{
  const int A = 300*1024, B = 256*768, C = 256*256, E4 = NE*256*256;
  int total = A+B+C+E4;
  for (int idx = blockIdx.x*blockDim.x + threadIdx.x; idx < total; idx += gridDim.x*blockDim.x) {
    if (idx < A) {                      // xwT[k][j]: j<768 -> ioux_w[j][k], else fx_w[j-768][k]
      int k = idx>>10, j = idx&1023;
      xwT[idx] = (j<768) ? ioux_w[j*300+k] : fx_w[(j-768)*300+k];
    } else if (idx < A+B) {             // iouhT[q][j] = iouh_w[j][q]
      int r = idx-A; int q = r/768, j = r%768;
      iouhT[r] = iouh_w[j*256+q];
    } else if (idx < A+B+C) {           // fhT[q][i] = fh_w[i][q]
      int r = idx-A-B; int q = r>>8, i2 = r&255;
      fhT[r] = fh_w[i2*256+q];
    } else {                            // e2hT[e][q][i] = e2h_w[e][i][q]
      int r = idx-A-B-C; int e = r>>16, rr = r&65535, q = rr>>8, i2 = rr&255;
      e2hT[r] = e2h_w[e*65536 + i2*256 + q];
    }
  }
}

// ---------------- counting sort of internal children by (level, edge type) ---
__device__ __forceinline__ int level_of(int g){
  int l = 1;
  #pragma unroll
  for (int q=2;q<=8;q++) if (g >= g_offs[q]) l = q;
  return l;
}

__global__ void k_hist(const int* __restrict__ edge_type, int* __restrict__ hist)
{
  for (int t = blockIdx.x*blockDim.x + threadIdx.x; t < NICH; t += gridDim.x*blockDim.x) {
    int g = NLEAF + (t>>2);
    int l = level_of(g);
    int et = edge_type[g*4 + (t&3)];
    atomicAdd(&hist[(l-1)*NE + et], 1);
  }
}

__global__ void k_prefix(const int* __restrict__ hist, int* __restrict__ cur, int* __restrict__ ptot)
{
  int l = threadIdx.x;
  if (l < 8) {
    int base = 0;
    for (int e=0;e<NE;e++){ cur[l*NE+e] = base; base += ((hist[l*NE+e]+31)>>5)<<5; }
    ptot[l] = base;   // padded child count for level l+1
  }
}

__global__ void k_scatter(const int* __restrict__ edge_type, int* __restrict__ cur, int* __restrict__ perm)
{
  for (int t = blockIdx.x*blockDim.x + threadIdx.x; t < NICH; t += gridDim.x*blockDim.x) {
    int g = NLEAF + (t>>2);
    int l = level_of(g);
    int c = t&3;
    int et = edge_type[g*4 + c];
    int p = g - g_offs[l];
    int k = 4*p + c;                    // child slot within level
    int pos = atomicAdd(&cur[(l-1)*NE + et], 1);
    perm[g_offs[l-1] + (l-1)*PERMPAD + pos] = k;
  }
}

// ---------------- leaf level: iou = x @ ioux_w.T + b -> h,c -------------------
__launch_bounds__(256)
__global__ void k_leaf(const float* __restrict__ x, const float* __restrict__ xwT,
                       const float* __restrict__ ioux_b, const float* __restrict__ iouh_b,
                       float* __restrict__ h_all, float* __restrict__ c_all)
{
  int i = threadIdx.x;
  int n0 = blockIdx.x * 32;
  __shared__ float xs[32][12];
  float aI[32], aO[32], aU[32];
  #pragma unroll
  for (int n=0;n<32;n++){ aI[n]=0.0f; aO[n]=0.0f; aU[n]=0.0f; }
  for (int kc=0; kc<25; ++kc) {
    __syncthreads();
    for (int e = i; e < 384; e += 256) {
      int n = e / 12, kk = e % 12;
      xs[n][kk] = x[(size_t)(n0+n)*300 + kc*12 + kk];
    }
    __syncthreads();
    float wI[12], wO[12], wU[12];
    #pragma unroll
    for (int kk=0;kk<12;kk++){
      int row = (kc*12+kk)*1024;
      wI[kk] = xwT[row + i];
      wO[kk] = xwT[row + 256 + i];
      wU[kk] = xwT[row + 512 + i];
    }
    #pragma unroll
    for (int kk=0;kk<12;kk++){
      #pragma unroll
      for (int n=0;n<32;n++){
        float xv = xs[n][kk];
        aI[n] += wI[kk]*xv;
        aO[n] += wO[kk]*xv;
        aU[n] += wU[kk]*xv;
      }
    }
  }
  float bi = ioux_b[i]     + iouh_b[i];
  float bo = ioux_b[256+i] + iouh_b[256+i];
  float bu = ioux_b[512+i] + iouh_b[512+i];
  #pragma unroll
  for (int n=0;n<32;n++){
    float ig = sigm(aI[n]+bi);
    float og = sigm(aO[n]+bo);
    float uu = tanhf(aU[n]+bu);
    float cc = ig*uu;
    float hh = og*tanhf(cc);
    c_all[(size_t)(n0+n)*H + i] = cc;
    h_all[(size_t)(n0+n)*H + i] = hh;
  }
}

// ------- per level: Y[k]=e2h_w[et]@h_k (atomic-> hsum) and fh_pre[k]=fh_w@h_k -
__launch_bounds__(256)
__global__ void k_e2hfh(const float* __restrict__ h_all, const int* __restrict__ edge_type,
                        const int* __restrict__ perm, const int* __restrict__ ptot,
                        const float* __restrict__ e2hT, const float* __restrict__ fhT,
                        float* __restrict__ hsum, float* __restrict__ fh_pre,
                        int lvl)
{
  int childbase = g_offs[lvl-1];
  int nodebase  = g_offs[lvl];
  int permbase  = childbase + (lvl-1)*PERMPAD;
  int j0 = blockIdx.x * 32;
  if (j0 >= ptot[lvl-1]) return;     // past padded region
  int i = threadIdx.x;
  __shared__ float hs[32][H];
  __shared__ int ks[32];
  if (i < 32) ks[i] = perm[permbase + j0 + i];
  __syncthreads();
  #pragma unroll 4
  for (int n=0;n<32;n++){
    int k = ks[n];
    hs[n][i] = (k >= 0) ? h_all[(size_t)(childbase + k)*H + i] : 0.0f;
  }
  __syncthreads();
  int k0 = ks[0];   // first slot of a type-uniform block is always real
  int e = edge_type[(nodebase + (k0>>2))*4 + (k0&3)];
  const float* we_base = e2hT + (size_t)e*H*H;
  float aY[32], aF[32];
  #pragma unroll
  for (int n=0;n<32;n++){ aY[n]=0.0f; aF[n]=0.0f; }
  for (int q4=0;q4<H/4;q4++){
    int q = q4*4;
    float we0 = we_base[(q+0)*H + i];
    float we1 = we_base[(q+1)*H + i];
    float we2 = we_base[(q+2)*H + i];
    float we3 = we_base[(q+3)*H + i];
    float wf0 = fhT[(q+0)*H + i];
    float wf1 = fhT[(q+1)*H + i];
    float wf2 = fhT[(q+2)*H + i];
    float wf3 = fhT[(q+3)*H + i];
    #pragma unroll
    for (int n=0;n<32;n++){
      const float4 hv = *reinterpret_cast<const float4*>(&hs[n][q]);
      aY[n] += we0*hv.x + we1*hv.y + we2*hv.z + we3*hv.w;
      aF[n] += wf0*hv.x + wf1*hv.y + wf2*hv.z + wf3*hv.w;
    }
  }
  #pragma unroll 4
  for (int n=0;n<32;n++){
    int k = ks[n];
    if (k >= 0){
      int p = k>>2;
      atomicAdd(&hsum[(size_t)(nodebase - NLEAF + p)*H + i], aY[n]);
      fh_pre[(size_t)k*H + i] = aF[n];
    }
  }
}

// ------- per level: iou/fx GEMMs + gates -> h,c ------------------------------
__launch_bounds__(256)
__global__ void k_node(const float* __restrict__ x, const float* __restrict__ xwT,
                       const float* __restrict__ iouhT,
                       const float* __restrict__ ioux_b, const float* __restrict__ iouh_b,
                       const float* __restrict__ fx_b, const float* __restrict__ fh_b,
                       const float* __restrict__ hsum, const float* __restrict__ fh_pre,
                       float* __restrict__ h_all, float* __restrict__ c_all,
                       int lvl)
{
  int s = g_offs[lvl];
  int m = g_offs[lvl+1]-s;
  int childbase = g_offs[lvl-1];
  int n0 = blockIdx.x * 16;
  int i = threadIdx.x;
  __shared__ float xs[16][12];
  __shared__ float hss[16][16];
  float aI[16], aO[16], aU[16], aX[16];
  #pragma unroll
  for (int n=0;n<16;n++){ aI[n]=0.0f; aO[n]=0.0f; aU[n]=0.0f; aX[n]=0.0f; }
  const float* hsumL = hsum + (size_t)(s - NLEAF)*H;

  for (int kc=0;kc<25;kc++){
    __syncthreads();
    if (i < 192){
      int n = i/12, kk = i%12;
      xs[n][kk] = (n0+n < m) ? x[(size_t)(s+n0+n)*300 + kc*12+kk] : 0.0f;
    }
    __syncthreads();
    float w0[12], w1[12], w2[12], w3[12];
    #pragma unroll
    for (int kk=0;kk<12;kk++){
      int row = (kc*12+kk)*1024;
      w0[kk]=xwT[row+i]; w1[kk]=xwT[row+256+i]; w2[kk]=xwT[row+512+i]; w3[kk]=xwT[row+768+i];
    }
    #pragma unroll
    for (int kk=0;kk<12;kk++){
      #pragma unroll
      for (int n=0;n<16;n++){
        float xv = xs[n][kk];
        aI[n]+=w0[kk]*xv; aO[n]+=w1[kk]*xv; aU[n]+=w2[kk]*xv; aX[n]+=w3[kk]*xv;
      }
    }
  }
  for (int qc=0;qc<16;qc++){
    __syncthreads();
    {
      int n = i>>4, qq = i&15;
      hss[n][qq] = (n0+n < m) ? hsumL[(size_t)(n0+n)*H + qc*16+qq] : 0.0f;
    }
    __syncthreads();
    float v0[16], v1[16], v2[16];
    #pragma unroll
    for (int qq=0;qq<16;qq++){
      int row=(qc*16+qq)*768;
      v0[qq]=iouhT[row+i]; v1[qq]=iouhT[row+256+i]; v2[qq]=iouhT[row+512+i];
    }
    #pragma unroll
    for (int qq=0;qq<16;qq++){
      #pragma unroll
      for (int n=0;n<16;n++){
        float hv = hss[n][qq];
        aI[n]+=v0[qq]*hv; aO[n]+=v1[qq]*hv; aU[n]+=v2[qq]*hv;
      }
    }
  }
  float bi = ioux_b[i]+iouh_b[i];
  float bo = ioux_b[256+i]+iouh_b[256+i];
  float bu = ioux_b[512+i]+iouh_b[512+i];
  float bf = fx_b[i]+fh_b[i];
  #pragma unroll
  for (int n=0;n<16;n++){
    int p = n0+n;
    if (p < m){
      float ig = sigm(aI[n]+bi);
      float og = sigm(aO[n]+bo);
      float uu = tanhf(aU[n]+bu);
      float fxv = aX[n]+bf;
      float fc = 0.0f;
      #pragma unroll
      for (int c=0;c<4;c++){
        int k = 4*p+c;
        float f = sigm(fh_pre[(size_t)k*H + i] + fxv);
        fc += f * c_all[(size_t)(childbase + k)*H + i];
      }
      float cc = ig*uu + fc;
      float hh = og*tanhf(cc);
      c_all[(size_t)(s+p)*H + i] = cc;
      h_all[(size_t)(s+p)*H + i] = hh;
    }
  }
}

__global__ void k_out(const float* __restrict__ h_all, const float* __restrict__ c_all,
                      float* __restrict__ out)
{
  int i = threadIdx.x;
  out[i]     = c_all[(size_t)(NTOT-1)*H + i];
  out[256+i] = h_all[(size_t)(NTOT-1)*H + i];
}

// -----------------------------------------------------------------------------
extern "C" void kernel_launch(void* const* d_in, const int* in_sizes, int n_in,
                              void* d_out, int out_size, void* d_ws, size_t ws_size,
                              hipStream_t stream)
{
  const float* x        = (const float*)d_in[0];
  const int*   edge_type= (const int*)d_in[2];
  const float* e2h_w    = (const float*)d_in[5];
  const float* ioux_w   = (const float*)d_in[6];
  const float* ioux_b   = (const float*)d_in[7];
  const float* iouh_w   = (const float*)d_in[8];
  const float* iouh_b   = (const float*)d_in[9];
  const float* fx_w     = (const float*)d_in[10];
  const float* fx_b     = (const float*)d_in[11];
  const float* fh_w     = (const float*)d_in[12];
  const float* fh_b     = (const float*)d_in[13];
  float* out = (float*)d_out;

  char* ws = (char*)d_ws;
  size_t o = 0;
  auto alloc = [&](size_t bytes){ size_t r = o; o += (bytes + 255) & ~(size_t)255; return r; };
  size_t off_h    = alloc((size_t)NTOT*H*4);
  size_t off_c    = alloc((size_t)NTOT*H*4);
  size_t off_xwT  = alloc((size_t)300*1024*4);
  size_t off_iouhT= alloc((size_t)256*768*4);
  size_t off_fhT  = alloc((size_t)256*256*4);
  size_t off_e2hT = alloc((size_t)NE*65536*4);
  size_t off_hsum = alloc((size_t)NINT*H*4);
  size_t off_fhpre= alloc((size_t)NLEAF*H*4);
  size_t off_perm = alloc((size_t)(NICH + 8*PERMPAD)*4);
  size_t off_hist = alloc(8*NE*4);
  size_t off_cur  = alloc(8*NE*4);
  size_t off_ptot = alloc(8*4);

  float* h_all  = (float*)(ws + off_h);
  float* c_all  = (float*)(ws + off_c);
  float* xwT    = (float*)(ws + off_xwT);
  float* iouhT  = (float*)(ws + off_iouhT);
  float* fhT    = (float*)(ws + off_fhT);
  float* e2hT   = (float*)(ws + off_e2hT);
  float* hsum   = (float*)(ws + off_hsum);
  float* fh_pre = (float*)(ws + off_fhpre);
  int*   perm   = (int*)(ws + off_perm);
  int*   hist   = (int*)(ws + off_hist);
  int*   cur    = (int*)(ws + off_cur);
  int*   ptot   = (int*)(ws + off_ptot);

  hipMemsetAsync(hist, 0, 8*NE*4, stream);
  hipMemsetAsync(perm, 0xFF, (size_t)(NICH + 8*PERMPAD)*4, stream);
  hipMemsetAsync(hsum, 0, (size_t)NINT*H*4, stream);

  k_transpose<<<1024, 256, 0, stream>>>(ioux_w, fx_w, iouh_w, fh_w, e2h_w,
                                        xwT, iouhT, fhT, e2hT);
  k_hist   <<<256, 256, 0, stream>>>(edge_type, hist);
  k_prefix <<<1,   64,  0, stream>>>(hist, cur, ptot);
  k_scatter<<<256, 256, 0, stream>>>(edge_type, cur, perm);

  k_leaf<<<NLEAF/32, 256, 0, stream>>>(x, xwT, ioux_b, iouh_b, h_all, c_all);

  for (int l=1; l<=8; ++l){
    int nch  = h_offs[l] - h_offs[l-1];          // children of this level
    int nblk = (nch + NE*31 + 31)/32;            // worst-case padded blocks
    k_e2hfh<<<nblk, 256, 0, stream>>>(h_all, edge_type, perm, ptot, e2hT, fhT,
                                      hsum, fh_pre, l);
    int m = h_offs[l+1] - h_offs[l];
    k_node<<<(m+15)/16, 256, 0, stream>>>(x, xwT, iouhT, ioux_b, iouh_b, fx_b, fh_b,
                                          hsum, fh_pre, h_all, c_all, l);
  }
  k_out<<<1, 256, 0, stream>>>(h_all, c_all, out);
}

// Round 2
// 1032.879 us; speedup vs baseline: 3.3814x; 3.3814x over previous
//
#include <hip/hip_runtime.h>
#include <math.h>

#define H 256
#define D 300
#define NE 37
#define NLEAF 65536
#define NTOT 87381
#define NINT 21845
#define NICH 87380
#define PERMPAD 1184     // 37*32
#define KX 320           // padded x-K
#define KN 576           // node GEMM K = 320 + 256
#define NROWS 87424

typedef __attribute__((ext_vector_type(8))) short short8;
typedef __attribute__((ext_vector_type(4))) float f32x4;

__device__ const int g_offs[10] = {0,65536,81920,86016,87040,87296,87360,87376,87380,87381};
static const int h_offs[10]     = {0,65536,81920,86016,87040,87296,87360,87376,87380,87381};

__device__ __forceinline__ float sigm(float v){ return 1.0f/(1.0f+__expf(-v)); }
__device__ __forceinline__ unsigned short f2bf(float f){
  unsigned int u = __float_as_uint(f);
  return (unsigned short)((u + 0x7fffu + ((u>>16)&1u)) >> 16);
}
__device__ __forceinline__ float bf2f(unsigned short v){ return __uint_as_float(((unsigned int)v)<<16); }

// ---------------- conversions ------------------------------------------------
__global__ void k_convx(const float* __restrict__ x, unsigned short* __restrict__ xb)
{
  size_t total = (size_t)NROWS*KX;
  for (size_t idx = (size_t)blockIdx.x*blockDim.x + threadIdx.x; idx < total;
       idx += (size_t)gridDim.x*blockDim.x) {
    int p = (int)(idx/KX), k = (int)(idx%KX);
    float v = (p < NTOT && k < D) ? x[(size_t)p*D + k] : 0.f;
    xb[idx] = f2bf(v);
  }
}

__global__ void k_convw(const float* __restrict__ ioux_w, const float* __restrict__ fx_w,
                        const float* __restrict__ iouh_w, const float* __restrict__ fh_w,
                        const float* __restrict__ e2h_w,
                        unsigned short* __restrict__ WN, unsigned short* __restrict__ WE)
{
  const int TOTN = 1024*KN;
  const int TOTE = NE*512*256;
  for (int idx = blockIdx.x*blockDim.x + threadIdx.x; idx < TOTN+TOTE;
       idx += gridDim.x*blockDim.x) {
    if (idx < TOTN) {
      int n = idx/KN, k = idx%KN;
      float v = 0.f;
      if (k < D)        v = (n < 768) ? ioux_w[n*D + k] : fx_w[(n-768)*D + k];
      else if (k >= KX && n < 768) v = iouh_w[n*H + (k-KX)];
      WN[idx] = f2bf(v);
    } else {
      int r = idx - TOTN;
      int e = r/(512*256), rr = r%(512*256), n = rr>>8, k = rr&255;
      float v = (n < 256) ? e2h_w[(size_t)e*65536 + n*256 + k] : fh_w[(n-256)*256 + k];
      WE[r] = f2bf(v);
    }
  }
}

// ---------------- counting sort of internal children by (level, type) --------
__device__ __forceinline__ int level_of(int g){
  int l = 1;
  #pragma unroll
  for (int q=2;q<=8;q++) if (g >= g_offs[q]) l = q;
  return l;
}

__global__ void k_hist(const int* __restrict__ edge_type, int* __restrict__ hist)
{
  for (int t = blockIdx.x*blockDim.x + threadIdx.x; t < NICH; t += gridDim.x*blockDim.x) {
    int g = NLEAF + (t>>2);
    int l = level_of(g);
    int et = edge_type[g*4 + (t&3)];
    atomicAdd(&hist[(l-1)*NE + et], 1);
  }
}

__global__ void k_prefix(const int* __restrict__ hist, int* __restrict__ cur, int* __restrict__ ptot)
{
  int l = threadIdx.x;
  if (l < 8) {
    int base = 0;
    for (int e=0;e<NE;e++){ cur[l*NE+e] = base; base += ((hist[l*NE+e]+31)>>5)<<5; }
    ptot[l] = base;
  }
}

__global__ void k_scatter(const int* __restrict__ edge_type, int* __restrict__ cur, int* __restrict__ perm)
{
  for (int t = blockIdx.x*blockDim.x + threadIdx.x; t < NICH; t += gridDim.x*blockDim.x) {
    int g = NLEAF + (t>>2);
    int l = level_of(g);
    int c = t&3;
    int et = edge_type[g*4 + c];
    int p = g - g_offs[l];
    int pos = atomicAdd(&cur[(l-1)*NE + et], 1);
    perm[g_offs[l-1] + (l-1)*PERMPAD + pos] = 4*p + c;
  }
}

// ---------------- generic 128x128 bf16 MFMA GEMM -----------------------------
// out[m][n] = sum_k A'[m][k] * B[n][k],  A' = [A1 (k<kc1*32) | A2]
__launch_bounds__(256)
__global__ void k_gemm(const unsigned short* __restrict__ A1, int lda1,
                       const unsigned short* __restrict__ A2, int lda2,
                       const unsigned short* __restrict__ B, int ldb,
                       int M, int ksteps, int kc1,
                       unsigned short* __restrict__ outb, int ldo)
{
  __shared__ __align__(16) unsigned short As[128*40];
  __shared__ __align__(16) unsigned short Bs[128*40];
  int m0 = blockIdx.x*128, n0 = blockIdx.y*128;
  int tid = threadIdx.x, lane = tid&63, wave = tid>>6;
  int wm = (wave&1)*64, wn = (wave>>1)*64;
  f32x4 acc[4][4] = {};
  int ar = lane&15, kb = (lane>>4)*8;

  for (int kc=0; kc<ksteps; ++kc){
    __syncthreads();
    #pragma unroll
    for (int rep=0; rep<2; ++rep){
      int u = tid + rep*256;
      int row = u>>2, seg = u&3;
      int gm = m0 + row;
      short8 v = {0,0,0,0,0,0,0,0};
      if (gm < M){
        const unsigned short* p = (kc < kc1)
          ? (A1 + (size_t)gm*lda1 + kc*32 + seg*8)
          : (A2 + (size_t)gm*lda2 + (kc-kc1)*32 + seg*8);
        v = *reinterpret_cast<const short8*>(p);
      }
      *reinterpret_cast<short8*>(&As[row*40 + seg*8]) = v;
      const unsigned short* q = B + (size_t)(n0+row)*ldb + kc*32 + seg*8;
      *reinterpret_cast<short8*>(&Bs[row*40 + seg*8]) = *reinterpret_cast<const short8*>(q);
    }
    __syncthreads();
    short8 af[4], bfr[4];
    #pragma unroll
    for (int f=0; f<4; ++f){
      af[f]  = *reinterpret_cast<const short8*>(&As[(wm + f*16 + ar)*40 + kb]);
      bfr[f] = *reinterpret_cast<const short8*>(&Bs[(wn + f*16 + ar)*40 + kb]);
    }
    #pragma unroll
    for (int i=0;i<4;i++)
      #pragma unroll
      for (int j=0;j<4;j++)
        acc[i][j] = __builtin_amdgcn_mfma_f32_16x16x32_bf16(af[i], bfr[j], acc[i][j], 0,0,0);
  }

  int rr = (lane>>4)*4, cc = lane&15;
  #pragma unroll
  for (int i=0;i<4;i++){
    #pragma unroll
    for (int r=0;r<4;r++){
      int gm = m0 + wm + i*16 + rr + r;
      if (gm < M){
        #pragma unroll
        for (int j=0;j<4;j++){
          int gn = n0 + wn + j*16 + cc;
          outb[(size_t)gm*ldo + gn] = f2bf(acc[i][j][r]);
        }
      }
    }
  }
}

// ---------------- per-level child GEMM: [e2h|fh] per type-block --------------
// ybuf[k][0:256) = e2h_w[et] @ h_k ; ybuf[k][256:512) = fh_w @ h_k
__launch_bounds__(256)
__global__ void k_gemm_ch(const unsigned short* __restrict__ hb, const int* __restrict__ edge_type,
                          const int* __restrict__ perm, const int* __restrict__ ptot,
                          const unsigned short* __restrict__ WE,
                          unsigned short* __restrict__ ybuf, int lvl)
{
  int childbase = g_offs[lvl-1];
  int nodebase  = g_offs[lvl];
  int permbase  = childbase + (lvl-1)*PERMPAD;
  int j0 = blockIdx.x*32;
  if (j0 >= ptot[lvl-1]) return;

  __shared__ __align__(16) unsigned short As[32*40];
  __shared__ __align__(16) unsigned short Bs[512*40];
  __shared__ int ks[32];
  int tid = threadIdx.x, lane = tid&63, wave = tid>>6;
  if (tid < 32) ks[tid] = perm[permbase + j0 + tid];
  __syncthreads();
  int k0 = ks[0];
  int e = edge_type[(nodebase + (k0>>2))*4 + (k0&3)];
  const unsigned short* WEe = WE + (size_t)e*512*256;
  f32x4 acc[2][8] = {};
  int ar = lane&15, kb = (lane>>4)*8;

  for (int kc=0; kc<8; ++kc){
    __syncthreads();
    if (tid < 128){
      int row = tid>>2, seg = tid&3;
      int k = ks[row];
      short8 v = {0,0,0,0,0,0,0,0};
      if (k >= 0)
        v = *reinterpret_cast<const short8*>(hb + (size_t)(childbase+k)*H + kc*32 + seg*8);
      *reinterpret_cast<short8*>(&As[row*40 + seg*8]) = v;
    }
    #pragma unroll
    for (int rep=0; rep<8; ++rep){
      int u = tid + rep*256;
      int row = u>>2, seg = u&3;
      *reinterpret_cast<short8*>(&Bs[row*40 + seg*8]) =
        *reinterpret_cast<const short8*>(WEe + (size_t)row*256 + kc*32 + seg*8);
    }
    __syncthreads();
    short8 af[2], bfr[8];
    af[0] = *reinterpret_cast<const short8*>(&As[(ar)*40 + kb]);
    af[1] = *reinterpret_cast<const short8*>(&As[(16+ar)*40 + kb]);
    #pragma unroll
    for (int j=0;j<8;j++)
      bfr[j] = *reinterpret_cast<const short8*>(&Bs[(wave*128 + j*16 + ar)*40 + kb]);
    #pragma unroll
    for (int i=0;i<2;i++)
      #pragma unroll
      for (int j=0;j<8;j++)
        acc[i][j] = __builtin_amdgcn_mfma_f32_16x16x32_bf16(af[i], bfr[j], acc[i][j], 0,0,0);
  }

  int rr = (lane>>4)*4, cc = lane&15;
  #pragma unroll
  for (int i=0;i<2;i++){
    #pragma unroll
    for (int r=0;r<4;r++){
      int ml = i*16 + rr + r;
      int k = ks[ml];
      if (k >= 0){
        #pragma unroll
        for (int j=0;j<8;j++){
          int n = wave*128 + j*16 + cc;
          ybuf[(size_t)k*512 + n] = f2bf(acc[i][j][r]);
        }
      }
    }
  }
}

// ---------------- sum 4 children e2h outputs -> hsumb (bf16) -----------------
__global__ void k_reduce4(const unsigned short* __restrict__ ybuf,
                          unsigned short* __restrict__ hsumb, int m)
{
  int u = blockIdx.x*blockDim.x + threadIdx.x;
  if (u >= m*32) return;
  int p = u>>5, i0 = (u&31)*8;
  float s[8] = {0,0,0,0,0,0,0,0};
  #pragma unroll
  for (int c=0;c<4;c++){
    short8 v = *reinterpret_cast<const short8*>(ybuf + (size_t)(4*p+c)*512 + i0);
    #pragma unroll
    for (int j=0;j<8;j++) s[j] += bf2f((unsigned short)v[j]);
  }
  short8 o;
  #pragma unroll
  for (int j=0;j<8;j++) o[j] = (short)f2bf(s[j]);
  *reinterpret_cast<short8*>(hsumb + (size_t)p*H + i0) = o;
}

// ---------------- gate kernels ----------------------------------------------
__global__ void k_gate_leaf(const unsigned short* __restrict__ iou,
                            const float* __restrict__ ioux_b, const float* __restrict__ iouh_b,
                            float* __restrict__ c_all, unsigned short* __restrict__ hb)
{
  int u = blockIdx.x*blockDim.x + threadIdx.x;
  if (u >= NLEAF*32) return;
  int p = u>>5, i0 = (u&31)*8;
  short8 vi = *reinterpret_cast<const short8*>(iou + (size_t)p*768 + i0);
  short8 vo = *reinterpret_cast<const short8*>(iou + (size_t)p*768 + 256 + i0);
  short8 vu = *reinterpret_cast<const short8*>(iou + (size_t)p*768 + 512 + i0);
  short8 ho;
  float cs[8];
  #pragma unroll
  for (int j=0;j<8;j++){
    int i = i0+j;
    float ig = sigm(bf2f((unsigned short)vi[j]) + ioux_b[i]     + iouh_b[i]);
    float og = sigm(bf2f((unsigned short)vo[j]) + ioux_b[256+i] + iouh_b[256+i]);
    float uu = tanhf(bf2f((unsigned short)vu[j]) + ioux_b[512+i] + iouh_b[512+i]);
    float cc = ig*uu;
    cs[j] = cc;
    ho[j] = (short)f2bf(og*tanhf(cc));
  }
  float* cp = c_all + (size_t)p*H + i0;
  *reinterpret_cast<float4*>(cp)   = make_float4(cs[0],cs[1],cs[2],cs[3]);
  *reinterpret_cast<float4*>(cp+4) = make_float4(cs[4],cs[5],cs[6],cs[7]);
  *reinterpret_cast<short8*>(hb + (size_t)p*H + i0) = ho;
}

__global__ void k_gate_node(const unsigned short* __restrict__ iou,
                            const unsigned short* __restrict__ ybuf,
                            const float* __restrict__ ioux_b, const float* __restrict__ iouh_b,
                            const float* __restrict__ fx_b, const float* __restrict__ fh_b,
                            float* __restrict__ c_all, unsigned short* __restrict__ hb,
                            float* __restrict__ hroot, int lvl, int m)
{
  int u = blockIdx.x*blockDim.x + threadIdx.x;
  if (u >= m*32) return;
  int p = u>>5, i0 = (u&31)*8;
  int s = g_offs[lvl], childbase = g_offs[lvl-1];
  short8 vi = *reinterpret_cast<const short8*>(iou + (size_t)p*1024 + i0);
  short8 vo = *reinterpret_cast<const short8*>(iou + (size_t)p*1024 + 256 + i0);
  short8 vu = *reinterpret_cast<const short8*>(iou + (size_t)p*1024 + 512 + i0);
  short8 vx = *reinterpret_cast<const short8*>(iou + (size_t)p*1024 + 768 + i0);
  float fxv[8], fc[8];
  #pragma unroll
  for (int j=0;j<8;j++){
    int i = i0+j;
    fxv[j] = bf2f((unsigned short)vx[j]) + fx_b[i] + fh_b[i];
    fc[j] = 0.f;
  }
  #pragma unroll
  for (int c=0;c<4;c++){
    int k = 4*p + c;
    short8 vf = *reinterpret_cast<const short8*>(ybuf + (size_t)k*512 + 256 + i0);
    const float* cp = c_all + (size_t)(childbase+k)*H + i0;
    float4 c0 = *reinterpret_cast<const float4*>(cp);
    float4 c1 = *reinterpret_cast<const float4*>(cp+4);
    float cv[8] = {c0.x,c0.y,c0.z,c0.w,c1.x,c1.y,c1.z,c1.w};
    #pragma unroll
    for (int j=0;j<8;j++)
      fc[j] += sigm(bf2f((unsigned short)vf[j]) + fxv[j]) * cv[j];
  }
  short8 ho;
  float cs[8];
  #pragma unroll
  for (int j=0;j<8;j++){
    int i = i0+j;
    float ig = sigm(bf2f((unsigned short)vi[j]) + ioux_b[i]     + iouh_b[i]);
    float og = sigm(bf2f((unsigned short)vo[j]) + ioux_b[256+i] + iouh_b[256+i]);
    float uu = tanhf(bf2f((unsigned short)vu[j]) + ioux_b[512+i] + iouh_b[512+i]);
    float cc = ig*uu + fc[j];
    float hh = og*tanhf(cc);
    cs[j] = cc;
    ho[j] = (short)f2bf(hh);
    if (s+p == NTOT-1) hroot[i] = hh;
  }
  float* cp = c_all + (size_t)(s+p)*H + i0;
  *reinterpret_cast<float4*>(cp)   = make_float4(cs[0],cs[1],cs[2],cs[3]);
  *reinterpret_cast<float4*>(cp+4) = make_float4(cs[4],cs[5],cs[6],cs[7]);
  *reinterpret_cast<short8*>(hb + (size_t)(s+p)*H + i0) = ho;
}

__global__ void k_out(const float* __restrict__ c_all, const float* __restrict__ hroot,
                      float* __restrict__ out)
{
  int i = threadIdx.x;
  out[i]     = c_all[(size_t)(NTOT-1)*H + i];
  out[256+i] = hroot[i];
}

// -----------------------------------------------------------------------------
extern "C" void kernel_launch(void* const* d_in, const int* in_sizes, int n_in,
                              void* d_out, int out_size, void* d_ws, size_t ws_size,
                              hipStream_t stream)
{
  const float* x        = (const float*)d_in[0];
  const int*   edge_type= (const int*)d_in[2];
  const float* e2h_w    = (const float*)d_in[5];
  const float* ioux_w   = (const float*)d_in[6];
  const float* ioux_b   = (const float*)d_in[7];
  const float* iouh_w   = (const float*)d_in[8];
  const float* iouh_b   = (const float*)d_in[9];
  const float* fx_w     = (const float*)d_in[10];
  const float* fx_b     = (const float*)d_in[11];
  const float* fh_w     = (const float*)d_in[12];
  const float* fh_b     = (const float*)d_in[13];
  float* out = (float*)d_out;

  char* ws = (char*)d_ws;
  size_t o = 0;
  auto alloc = [&](size_t bytes){ size_t r = o; o += (bytes + 255) & ~(size_t)255; return r; };
  size_t off_xb    = alloc((size_t)NROWS*KX*2);        // 56.0 MB bf16 x (padded)
  size_t off_hb    = alloc((size_t)NROWS*H*2);         // 44.8 MB bf16 h
  size_t off_c     = alloc((size_t)NTOT*H*4);          // 89.5 MB fp32 c
  size_t off_WN    = alloc((size_t)1024*KN*2);         // 1.2 MB
  size_t off_WE    = alloc((size_t)NE*512*256*2);      // 9.7 MB
  size_t off_R1    = alloc((size_t)NLEAF*768*2);       // 100.7 MB: leaf iou, then ybuf
  size_t off_iouN  = alloc((size_t)NINT*1024*2);       // 44.8 MB node iou|fx
  size_t off_hsumb = alloc((size_t)16384*H*2);         // 8.4 MB
  size_t off_hroot = alloc(256*4);
  size_t off_perm  = alloc((size_t)(NICH + 8*PERMPAD)*4);
  size_t off_hist  = alloc(8*NE*4);
  size_t off_cur   = alloc(8*NE*4);
  size_t off_ptot  = alloc(8*4);

  unsigned short* xb    = (unsigned short*)(ws + off_xb);
  unsigned short* hb    = (unsigned short*)(ws + off_hb);
  float*          c_all = (float*)(ws + off_c);
  unsigned short* WN    = (unsigned short*)(ws + off_WN);
  unsigned short* WE    = (unsigned short*)(ws + off_WE);
  unsigned short* iouL  = (unsigned short*)(ws + off_R1);   // leaf iou
  unsigned short* ybuf  = (unsigned short*)(ws + off_R1);   // reused after gate_leaf
  unsigned short* iouN  = (unsigned short*)(ws + off_iouN);
  unsigned short* hsumb = (unsigned short*)(ws + off_hsumb);
  float*          hroot = (float*)(ws + off_hroot);
  int* perm = (int*)(ws + off_perm);
  int* hist = (int*)(ws + off_hist);
  int* cur  = (int*)(ws + off_cur);
  int* ptot = (int*)(ws + off_ptot);

  hipMemsetAsync(hist, 0, 8*NE*4, stream);
  hipMemsetAsync(perm, 0xFF, (size_t)(NICH + 8*PERMPAD)*4, stream);

  k_convx<<<4096, 256, 0, stream>>>(x, xb);
  k_convw<<<2048, 256, 0, stream>>>(ioux_w, fx_w, iouh_w, fh_w, e2h_w, WN, WE);
  k_hist   <<<256, 256, 0, stream>>>(edge_type, hist);
  k_prefix <<<1,   64,  0, stream>>>(hist, cur, ptot);
  k_scatter<<<256, 256, 0, stream>>>(edge_type, cur, perm);

  // leaves: iou = x @ [ioux]^T   (M=65536, N=768, K=320)
  k_gemm<<<dim3(NLEAF/128, 6), 256, 0, stream>>>(xb, KX, xb, KX, WN, KN,
                                                 NLEAF, 10, 10, iouL, 768);
  k_gate_leaf<<<NLEAF*32/256, 256, 0, stream>>>(iouL, ioux_b, iouh_b, c_all, hb);

  for (int l=1; l<=8; ++l){
    int s    = h_offs[l];
    int m    = h_offs[l+1] - s;
    int nch  = s - h_offs[l-1];
    int nblk = (nch + NE*31 + 31)/32;
    k_gemm_ch<<<nblk, 256, 0, stream>>>(hb, edge_type, perm, ptot, WE, ybuf, l);
    k_reduce4<<<(m*32+255)/256, 256, 0, stream>>>(ybuf, hsumb, m);
    // nodes: [iou|fx] = [x|hsum] @ WN^T  (N=1024, K=576)
    k_gemm<<<dim3((m+127)/128, 8), 256, 0, stream>>>(xb + (size_t)s*KX, KX,
                                                     hsumb, H, WN, KN,
                                                     m, 18, 10, iouN, 1024);
    k_gate_node<<<(m*32+255)/256, 256, 0, stream>>>(iouN, ybuf, ioux_b, iouh_b,
                                                    fx_b, fh_b, c_all, hb, hroot, l, m);
  }
  k_out<<<1, 256, 0, stream>>>(c_all, hroot, out);
}

// Round 3
// 845.523 us; speedup vs baseline: 4.1306x; 1.2216x over previous
//
#include <hip/hip_runtime.h>
#include <math.h>

#define H 256
#define D 300
#define NE 37
#define NLEAF 65536
#define NTOT 87381
#define NINT 21845
#define NICH 87380
#define PERMPAD 1184     // 37*32
#define KX 320           // padded x-K
#define KN 576           // node GEMM K = 320 + 256
#define NROWS 87424

typedef __attribute__((ext_vector_type(8))) short short8;
typedef __attribute__((ext_vector_type(4))) float f32x4;

__device__ const int g_offs[10] = {0,65536,81920,86016,87040,87296,87360,87376,87380,87381};
static const int h_offs[10]     = {0,65536,81920,86016,87040,87296,87360,87376,87380,87381};

__device__ __forceinline__ float frcp(float v){ return __builtin_amdgcn_rcpf(v); }
__device__ __forceinline__ float sigm(float v){ return frcp(1.0f + __expf(-v)); }
__device__ __forceinline__ float ftanh(float v){ return 1.0f - 2.0f*frcp(__expf(2.0f*v) + 1.0f); }
__device__ __forceinline__ unsigned short f2bf(float f){
  unsigned int u = __float_as_uint(f);
  return (unsigned short)((u + 0x7fffu + ((u>>16)&1u)) >> 16);
}
__device__ __forceinline__ float bf2f(unsigned short v){ return __uint_as_float(((unsigned int)v)<<16); }

// ---------------- conversions ------------------------------------------------
__global__ void k_convx(const float* __restrict__ x, unsigned short* __restrict__ xb)
{
  size_t total = (size_t)NROWS*KX;
  for (size_t idx = (size_t)blockIdx.x*blockDim.x + threadIdx.x; idx < total;
       idx += (size_t)gridDim.x*blockDim.x) {
    int p = (int)(idx/KX), k = (int)(idx%KX);
    float v = (p < NTOT && k < D) ? x[(size_t)p*D + k] : 0.f;
    xb[idx] = f2bf(v);
  }
}

__global__ void k_convw(const float* __restrict__ ioux_w, const float* __restrict__ fx_w,
                        const float* __restrict__ iouh_w, const float* __restrict__ fh_w,
                        const float* __restrict__ e2h_w,
                        unsigned short* __restrict__ WN, unsigned short* __restrict__ WE)
{
  const int TOTN = 1024*KN;
  const int TOTE = NE*512*256;
  for (int idx = blockIdx.x*blockDim.x + threadIdx.x; idx < TOTN+TOTE;
       idx += gridDim.x*blockDim.x) {
    if (idx < TOTN) {
      int n = idx/KN, k = idx%KN;
      float v = 0.f;
      if (k < D)        v = (n < 768) ? ioux_w[n*D + k] : fx_w[(n-768)*D + k];
      else if (k >= KX && n < 768) v = iouh_w[n*H + (k-KX)];
      WN[idx] = f2bf(v);
    } else {
      int r = idx - TOTN;
      int e = r/(512*256), rr = r%(512*256), n = rr>>8, k = rr&255;
      float v = (n < 256) ? e2h_w[(size_t)e*65536 + n*256 + k] : fh_w[(n-256)*256 + k];
      WE[r] = f2bf(v);
    }
  }
}

__global__ void k_bias(const float* __restrict__ ioux_b, const float* __restrict__ iouh_b,
                       const float* __restrict__ fx_b, const float* __restrict__ fh_b,
                       float* __restrict__ bias)
{
  int n = blockIdx.x*blockDim.x + threadIdx.x;
  if (n < 768)       bias[n] = ioux_b[n] + iouh_b[n];
  else if (n < 1024) bias[n] = fx_b[n-768] + fh_b[n-768];
}

// ---------------- counting sort of internal children by (level, type) --------
__device__ __forceinline__ int level_of(int g){
  int l = 1;
  #pragma unroll
  for (int q=2;q<=8;q++) if (g >= g_offs[q]) l = q;
  return l;
}

__global__ void k_hist(const int* __restrict__ edge_type, int* __restrict__ hist)
{
  for (int t = blockIdx.x*blockDim.x + threadIdx.x; t < NICH; t += gridDim.x*blockDim.x) {
    int g = NLEAF + (t>>2);
    int l = level_of(g);
    int et = edge_type[g*4 + (t&3)];
    atomicAdd(&hist[(l-1)*NE + et], 1);
  }
}

__global__ void k_prefix(const int* __restrict__ hist, int* __restrict__ cur, int* __restrict__ ptot)
{
  int l = threadIdx.x;
  if (l < 8) {
    int base = 0;
    for (int e=0;e<NE;e++){ cur[l*NE+e] = base; base += ((hist[l*NE+e]+31)>>5)<<5; }
    ptot[l] = base;
  }
}

__global__ void k_scatter(const int* __restrict__ edge_type, int* __restrict__ cur, int* __restrict__ perm)
{
  for (int t = blockIdx.x*blockDim.x + threadIdx.x; t < NICH; t += gridDim.x*blockDim.x) {
    int g = NLEAF + (t>>2);
    int l = level_of(g);
    int c = t&3;
    int et = edge_type[g*4 + c];
    int p = g - g_offs[l];
    int pos = atomicAdd(&cur[(l-1)*NE + et], 1);
    perm[g_offs[l-1] + (l-1)*PERMPAD + pos] = 4*p + c;
  }
}

// ---------------- fused GEMM + gates -----------------------------------------
// Per block: 64 nodes x 128 i-cols, G gate accumulators.
// Gate g pre-act = sum_k A'[p][k] * WN[g*256 + i][k]  (A' = [A1 | A2] split at kc1)
// Epilogue applies LSTM gate math entirely in-register; iou never hits memory.
template<int G>
__launch_bounds__(256, 2)
__global__ void k_gemm_gates(const unsigned short* __restrict__ A1, int lda1,
                             const unsigned short* __restrict__ A2, int lda2,
                             const unsigned short* __restrict__ WN,
                             const float* __restrict__ bias,
                             int M, int ksteps, int kc1,
                             const unsigned short* __restrict__ ybuf,   // node: f-part
                             const float* __restrict__ c_child,         // node: child c base
                             float* __restrict__ c_out,
                             unsigned short* __restrict__ h_out,
                             float* __restrict__ hroot, int rootrow)
{
  __shared__ __align__(16) unsigned short As[64*40];
  __shared__ __align__(16) unsigned short Bs[G*128*40];
  int m0 = blockIdx.x*64, n0r = blockIdx.y*128;
  int tid = threadIdx.x, lane = tid&63, wave = tid>>6;
  int wm = (wave&1)*32, wn = (wave>>1)*64;
  int ar = lane&15, kb = (lane>>4)*8;
  f32x4 acc[G][2][4] = {};

  for (int kc=0; kc<ksteps; ++kc){
    __syncthreads();
    {
      int row = tid>>2, seg = tid&3;
      int gm = m0 + row;
      short8 v = {0,0,0,0,0,0,0,0};
      if (gm < M){
        const unsigned short* p = (kc < kc1)
          ? (A1 + (size_t)gm*lda1 + kc*32 + seg*8)
          : (A2 + (size_t)gm*lda2 + (kc-kc1)*32 + seg*8);
        v = *reinterpret_cast<const short8*>(p);
      }
      *reinterpret_cast<short8*>(&As[row*40 + seg*8]) = v;
    }
    #pragma unroll
    for (int rep=0; rep<2*G; ++rep){
      int u = tid + rep*256;
      int row = u>>2, seg = u&3;        // row in [0, G*128)
      int g = row>>7, rr2 = row&127;
      const unsigned short* q = WN + (size_t)(g*256 + n0r + rr2)*KN + kc*32 + seg*8;
      *reinterpret_cast<short8*>(&Bs[row*40 + seg*8]) = *reinterpret_cast<const short8*>(q);
    }
    __syncthreads();
    short8 af[2];
    #pragma unroll
    for (int mi=0; mi<2; ++mi)
      af[mi] = *reinterpret_cast<const short8*>(&As[(wm + mi*16 + ar)*40 + kb]);
    #pragma unroll
    for (int g=0; g<G; ++g){
      #pragma unroll
      for (int nj=0; nj<4; ++nj){
        short8 bfr = *reinterpret_cast<const short8*>(&Bs[(g*128 + wn + nj*16 + ar)*40 + kb]);
        #pragma unroll
        for (int mi=0; mi<2; ++mi)
          acc[g][mi][nj] = __builtin_amdgcn_mfma_f32_16x16x32_bf16(af[mi], bfr, acc[g][mi][nj], 0,0,0);
      }
    }
  }

  int rr = (lane>>4)*4, cc = lane&15;
  #pragma unroll
  for (int mi=0; mi<2; ++mi){
    #pragma unroll
    for (int r=0; r<4; ++r){
      int p = m0 + wm + mi*16 + rr + r;
      if (p < M){
        #pragma unroll
        for (int nj=0; nj<4; ++nj){
          int i = n0r + wn + nj*16 + cc;
          float ig = sigm (acc[0][mi][nj][r] + bias[i]);
          float og = sigm (acc[1][mi][nj][r] + bias[256+i]);
          float uu = ftanh(acc[2][mi][nj][r] + bias[512+i]);
          float ccv = ig*uu;
          if (G == 4){
            float fxv = acc[3][mi][nj][r] + bias[768+i];
            float fc = 0.f;
            #pragma unroll
            for (int c=0;c<4;c++){
              int k = 4*p + c;
              fc += sigm(bf2f(ybuf[(size_t)k*512 + 256 + i]) + fxv)
                    * c_child[(size_t)k*H + i];
            }
            ccv += fc;
          }
          float hh = og*ftanh(ccv);
          c_out[(size_t)p*H + i] = ccv;
          h_out[(size_t)p*H + i] = f2bf(hh);
          if (G == 4 && p == rootrow) hroot[i] = hh;
        }
      }
    }
  }
}

// ---------------- per-level child GEMM: [e2h|fh] per type-block --------------
__launch_bounds__(256)
__global__ void k_gemm_ch(const unsigned short* __restrict__ hb, const int* __restrict__ edge_type,
                          const int* __restrict__ perm, const int* __restrict__ ptot,
                          const unsigned short* __restrict__ WE,
                          unsigned short* __restrict__ ybuf, int lvl)
{
  int childbase = g_offs[lvl-1];
  int nodebase  = g_offs[lvl];
  int permbase  = childbase + (lvl-1)*PERMPAD;
  int j0 = blockIdx.x*32;
  if (j0 >= ptot[lvl-1]) return;

  __shared__ __align__(16) unsigned short As[32*40];
  __shared__ __align__(16) unsigned short Bs[512*40];
  __shared__ int ks[32];
  int tid = threadIdx.x, lane = tid&63, wave = tid>>6;
  if (tid < 32) ks[tid] = perm[permbase + j0 + tid];
  __syncthreads();
  int k0 = ks[0];
  int e = edge_type[(nodebase + (k0>>2))*4 + (k0&3)];
  const unsigned short* WEe = WE + (size_t)e*512*256;
  f32x4 acc[2][8] = {};
  int ar = lane&15, kb = (lane>>4)*8;

  for (int kc=0; kc<8; ++kc){
    __syncthreads();
    if (tid < 128){
      int row = tid>>2, seg = tid&3;
      int k = ks[row];
      short8 v = {0,0,0,0,0,0,0,0};
      if (k >= 0)
        v = *reinterpret_cast<const short8*>(hb + (size_t)(childbase+k)*H + kc*32 + seg*8);
      *reinterpret_cast<short8*>(&As[row*40 + seg*8]) = v;
    }
    #pragma unroll
    for (int rep=0; rep<8; ++rep){
      int u = tid + rep*256;
      int row = u>>2, seg = u&3;
      *reinterpret_cast<short8*>(&Bs[row*40 + seg*8]) =
        *reinterpret_cast<const short8*>(WEe + (size_t)row*256 + kc*32 + seg*8);
    }
    __syncthreads();
    short8 af[2], bfr[8];
    af[0] = *reinterpret_cast<const short8*>(&As[(ar)*40 + kb]);
    af[1] = *reinterpret_cast<const short8*>(&As[(16+ar)*40 + kb]);
    #pragma unroll
    for (int j=0;j<8;j++)
      bfr[j] = *reinterpret_cast<const short8*>(&Bs[(wave*128 + j*16 + ar)*40 + kb]);
    #pragma unroll
    for (int i=0;i<2;i++)
      #pragma unroll
      for (int j=0;j<8;j++)
        acc[i][j] = __builtin_amdgcn_mfma_f32_16x16x32_bf16(af[i], bfr[j], acc[i][j], 0,0,0);
  }

  int rr = (lane>>4)*4, cc = lane&15;
  #pragma unroll
  for (int i=0;i<2;i++){
    #pragma unroll
    for (int r=0;r<4;r++){
      int ml = i*16 + rr + r;
      int k = ks[ml];
      if (k >= 0){
        #pragma unroll
        for (int j=0;j<8;j++){
          int n = wave*128 + j*16 + cc;
          ybuf[(size_t)k*512 + n] = f2bf(acc[i][j][r]);
        }
      }
    }
  }
}

// ---------------- sum 4 children e2h outputs -> hsumb (bf16) -----------------
__global__ void k_reduce4(const unsigned short* __restrict__ ybuf,
                          unsigned short* __restrict__ hsumb, int m)
{
  int u = blockIdx.x*blockDim.x + threadIdx.x;
  if (u >= m*32) return;
  int p = u>>5, i0 = (u&31)*8;
  float s[8] = {0,0,0,0,0,0,0,0};
  #pragma unroll
  for (int c=0;c<4;c++){
    short8 v = *reinterpret_cast<const short8*>(ybuf + (size_t)(4*p+c)*512 + i0);
    #pragma unroll
    for (int j=0;j<8;j++) s[j] += bf2f((unsigned short)v[j]);
  }
  short8 o;
  #pragma unroll
  for (int j=0;j<8;j++) o[j] = (short)f2bf(s[j]);
  *reinterpret_cast<short8*>(hsumb + (size_t)p*H + i0) = o;
}

__global__ void k_out(const float* __restrict__ c_all, const float* __restrict__ hroot,
                      float* __restrict__ out)
{
  int i = threadIdx.x;
  out[i]     = c_all[(size_t)(NTOT-1)*H + i];
  out[256+i] = hroot[i];
}

// -----------------------------------------------------------------------------
extern "C" void kernel_launch(void* const* d_in, const int* in_sizes, int n_in,
                              void* d_out, int out_size, void* d_ws, size_t ws_size,
                              hipStream_t stream)
{
  const float* x        = (const float*)d_in[0];
  const int*   edge_type= (const int*)d_in[2];
  const float* e2h_w    = (const float*)d_in[5];
  const float* ioux_w   = (const float*)d_in[6];
  const float* ioux_b   = (const float*)d_in[7];
  const float* iouh_w   = (const float*)d_in[8];
  const float* iouh_b   = (const float*)d_in[9];
  const float* fx_w     = (const float*)d_in[10];
  const float* fx_b     = (const float*)d_in[11];
  const float* fh_w     = (const float*)d_in[12];
  const float* fh_b     = (const float*)d_in[13];
  float* out = (float*)d_out;

  char* ws = (char*)d_ws;
  size_t o = 0;
  auto alloc = [&](size_t bytes){ size_t r = o; o += (bytes + 255) & ~(size_t)255; return r; };
  size_t off_xb    = alloc((size_t)NROWS*KX*2);        // 56 MB bf16 x (padded)
  size_t off_hb    = alloc((size_t)NROWS*H*2);         // 44.8 MB bf16 h
  size_t off_c     = alloc((size_t)NTOT*H*4);          // 89.5 MB fp32 c
  size_t off_WN    = alloc((size_t)1024*KN*2);         // 1.2 MB
  size_t off_WE    = alloc((size_t)NE*512*256*2);      // 9.7 MB
  size_t off_bias  = alloc(1024*4);
  size_t off_ybuf  = alloc((size_t)NLEAF*512*2);       // 67 MB
  size_t off_hsumb = alloc((size_t)16384*H*2);         // 8.4 MB
  size_t off_hroot = alloc(256*4);
  size_t off_perm  = alloc((size_t)(NICH + 8*PERMPAD)*4);
  size_t off_hist  = alloc(8*NE*4);
  size_t off_cur   = alloc(8*NE*4);
  size_t off_ptot  = alloc(8*4);

  unsigned short* xb    = (unsigned short*)(ws + off_xb);
  unsigned short* hb    = (unsigned short*)(ws + off_hb);
  float*          c_all = (float*)(ws + off_c);
  unsigned short* WN    = (unsigned short*)(ws + off_WN);
  unsigned short* WE    = (unsigned short*)(ws + off_WE);
  float*          bias  = (float*)(ws + off_bias);
  unsigned short* ybuf  = (unsigned short*)(ws + off_ybuf);
  unsigned short* hsumb = (unsigned short*)(ws + off_hsumb);
  float*          hroot = (float*)(ws + off_hroot);
  int* perm = (int*)(ws + off_perm);
  int* hist = (int*)(ws + off_hist);
  int* cur  = (int*)(ws + off_cur);
  int* ptot = (int*)(ws + off_ptot);

  hipMemsetAsync(hist, 0, 8*NE*4, stream);
  hipMemsetAsync(perm, 0xFF, (size_t)(NICH + 8*PERMPAD)*4, stream);

  k_convx<<<4096, 256, 0, stream>>>(x, xb);
  k_convw<<<2048, 256, 0, stream>>>(ioux_w, fx_w, iouh_w, fh_w, e2h_w, WN, WE);
  k_bias <<<4, 256, 0, stream>>>(ioux_b, iouh_b, fx_b, fh_b, bias);
  k_hist   <<<256, 256, 0, stream>>>(edge_type, hist);
  k_prefix <<<1,   64,  0, stream>>>(hist, cur, ptot);
  k_scatter<<<256, 256, 0, stream>>>(edge_type, cur, perm);

  // leaves: gates = x @ WN[iou]^T + b -> h,c fused  (M=65536, K=320)
  k_gemm_gates<3><<<dim3(NLEAF/64, 2), 256, 0, stream>>>(
      xb, KX, xb, KX, WN, bias, NLEAF, 10, 10,
      nullptr, nullptr, c_all, hb, nullptr, -1);

  for (int l=1; l<=8; ++l){
    int s    = h_offs[l];
    int m    = h_offs[l+1] - s;
    int childbase = h_offs[l-1];
    int nch  = s - childbase;
    int nblk = (nch + NE*31 + 31)/32;
    k_gemm_ch<<<nblk, 256, 0, stream>>>(hb, edge_type, perm, ptot, WE, ybuf, l);
    k_reduce4<<<(m*32+255)/256, 256, 0, stream>>>(ybuf, hsumb, m);
    // nodes: gates = [x|hsum] @ WN^T + b -> h,c fused  (K=576)
    k_gemm_gates<4><<<dim3((m+63)/64, 2), 256, 0, stream>>>(
        xb + (size_t)s*KX, KX, hsumb, H, WN, bias, m, 18, 10,
        ybuf, c_all + (size_t)childbase*H,
        c_all + (size_t)s*H, hb + (size_t)s*H,
        hroot, (l==8) ? 0 : -1);
  }
  k_out<<<1, 256, 0, stream>>>(c_all, hroot, out);
}

// Round 4
// 577.941 us; speedup vs baseline: 6.0431x; 1.4630x over previous
//
#include <hip/hip_runtime.h>
#include <math.h>

#define H 256
#define D 300
#define NE 37
#define NLEAF 65536
#define NTOT 87381
#define NINT 21845
#define NICH 87380
#define PERMPAD 1184     // 37*32
#define KX 320           // padded x-K
#define KN 576           // node GEMM K = 320 + 256
#define NROWS 87424
#define NBINS 296        // 8 levels * 37 types
#define HB 120           // histogram blocks
#define CHUNK 729        // ceil(NICH/HB)

typedef __attribute__((ext_vector_type(8))) short short8;
typedef __attribute__((ext_vector_type(4))) float f32x4;

__device__ const int g_offs[10] = {0,65536,81920,86016,87040,87296,87360,87376,87380,87381};
static const int h_offs[10]     = {0,65536,81920,86016,87040,87296,87360,87376,87380,87381};

__device__ __forceinline__ float frcp(float v){ return __builtin_amdgcn_rcpf(v); }
__device__ __forceinline__ float sigm(float v){ return frcp(1.0f + __expf(-v)); }
__device__ __forceinline__ float ftanh(float v){ return 1.0f - 2.0f*frcp(__expf(2.0f*v) + 1.0f); }
__device__ __forceinline__ unsigned short f2bf(float f){
  unsigned int u = __float_as_uint(f);
  return (unsigned short)((u + 0x7fffu + ((u>>16)&1u)) >> 16);
}
__device__ __forceinline__ float bf2f(unsigned short v){ return __uint_as_float(((unsigned int)v)<<16); }

// ---------------- conversions ------------------------------------------------
__global__ void k_convx(const float* __restrict__ x, unsigned short* __restrict__ xb)
{
  size_t total = (size_t)NROWS*KX/8;
  for (size_t v8 = (size_t)blockIdx.x*blockDim.x + threadIdx.x; v8 < total;
       v8 += (size_t)gridDim.x*blockDim.x) {
    int p = (int)(v8/40), k0 = (int)(v8%40)*8;
    short8 o;
    #pragma unroll
    for (int j=0;j<8;j++){
      int k = k0+j;
      float v = (p < NTOT && k < D) ? x[(size_t)p*D + k] : 0.f;
      o[j] = (short)f2bf(v);
    }
    *reinterpret_cast<short8*>(xb + v8*8) = o;
  }
}

__global__ void k_convw(const float* __restrict__ ioux_w, const float* __restrict__ fx_w,
                        const float* __restrict__ iouh_w, const float* __restrict__ fh_w,
                        const float* __restrict__ e2h_w,
                        unsigned short* __restrict__ WN, unsigned short* __restrict__ WE)
{
  const int TOTN = 1024*KN;
  const int TOTE = NE*512*256;
  for (int idx = blockIdx.x*blockDim.x + threadIdx.x; idx < TOTN+TOTE;
       idx += gridDim.x*blockDim.x) {
    if (idx < TOTN) {
      int n = idx/KN, k = idx%KN;
      float v = 0.f;
      if (k < D)        v = (n < 768) ? ioux_w[n*D + k] : fx_w[(n-768)*D + k];
      else if (k >= KX && n < 768) v = iouh_w[n*H + (k-KX)];
      WN[idx] = f2bf(v);
    } else {
      int r = idx - TOTN;
      int e = r/(512*256), rr = r%(512*256), n = rr>>8, k = rr&255;
      float v = (n < 256) ? e2h_w[(size_t)e*65536 + n*256 + k] : fh_w[(n-256)*256 + k];
      WE[r] = f2bf(v);
    }
  }
}

__global__ void k_bias(const float* __restrict__ ioux_b, const float* __restrict__ iouh_b,
                       const float* __restrict__ fx_b, const float* __restrict__ fh_b,
                       float* __restrict__ bias)
{
  int n = blockIdx.x*blockDim.x + threadIdx.x;
  if (n < 768)       bias[n] = ioux_b[n] + iouh_b[n];
  else if (n < 1024) bias[n] = fx_b[n-768] + fh_b[n-768];
}

// ---------------- counting sort (LDS histograms, no global atomics) ----------
__device__ __forceinline__ int level_of(int g){
  int l = 1;
  #pragma unroll
  for (int q=2;q<=8;q++) if (g >= g_offs[q]) l = q;
  return l;
}

__global__ void k_hist2(const int* __restrict__ edge_type, int* __restrict__ bhist)
{
  __shared__ int hs[NBINS];
  int b = blockIdx.x, tid = threadIdx.x;
  for (int i = tid; i < NBINS; i += 256) hs[i] = 0;
  __syncthreads();
  int t0 = b*CHUNK, t1 = min(t0+CHUNK, NICH);
  for (int t = t0 + tid; t < t1; t += 256){
    int g = NLEAF + (t>>2);
    int l = level_of(g);
    int et = edge_type[g*4 + (t&3)];
    atomicAdd(&hs[(l-1)*NE + et], 1);
  }
  __syncthreads();
  for (int i = tid; i < NBINS; i += 256) bhist[b*NBINS + i] = hs[i];
}

__global__ void k_scan(const int* __restrict__ bhist, int* __restrict__ boff,
                       int* __restrict__ ptot)
{
  __shared__ int tot[NBINS];
  __shared__ int base[NBINS];
  int tid = threadIdx.x;
  if (tid < NBINS){
    int s = 0;
    for (int b=0;b<HB;b++) s += bhist[b*NBINS + tid];
    tot[tid] = s;
  }
  __syncthreads();
  if (tid < 8){
    int acc = 0;
    for (int e=0;e<NE;e++){
      base[tid*NE + e] = acc;
      acc += ((tot[tid*NE + e] + 31)>>5)<<5;
    }
    ptot[tid] = acc;
  }
  __syncthreads();
  if (tid < NBINS){
    int run = base[tid];
    for (int b=0;b<HB;b++){
      boff[b*NBINS + tid] = run;
      run += bhist[b*NBINS + tid];
    }
  }
}

__global__ void k_scatter2(const int* __restrict__ edge_type, const int* __restrict__ boff,
                           int* __restrict__ perm)
{
  __shared__ int cnt[NBINS];
  int b = blockIdx.x, tid = threadIdx.x;
  for (int i = tid; i < NBINS; i += 256) cnt[i] = boff[b*NBINS + i];
  __syncthreads();
  int t0 = b*CHUNK, t1 = min(t0+CHUNK, NICH);
  for (int t = t0 + tid; t < t1; t += 256){
    int g = NLEAF + (t>>2);
    int l = level_of(g);
    int c = t&3;
    int et = edge_type[g*4 + c];
    int p = g - g_offs[l];
    int pos = atomicAdd(&cnt[(l-1)*NE + et], 1);
    perm[g_offs[l-1] + (l-1)*PERMPAD + pos] = 4*p + c;
  }
}

// ---------------- fused GEMM + gates -----------------------------------------
template<int G>
__launch_bounds__(256, 2)
__global__ void k_gemm_gates(const unsigned short* __restrict__ A1, int lda1,
                             const unsigned short* __restrict__ A2, int lda2,
                             const unsigned short* __restrict__ WN,
                             const float* __restrict__ bias,
                             int M, int ksteps, int kc1,
                             const unsigned short* __restrict__ ybuf,   // node: f-part
                             const float* __restrict__ c_child,         // node: child c base
                             float* __restrict__ c_out,
                             unsigned short* __restrict__ h_out,
                             float* __restrict__ hroot, int rootrow)
{
  __shared__ __align__(16) unsigned short As[64*40];
  __shared__ __align__(16) unsigned short Bs[G*128*40];
  int m0 = blockIdx.x*64, n0r = blockIdx.y*128;
  int tid = threadIdx.x, lane = tid&63, wave = tid>>6;
  int wm = (wave&1)*32, wn = (wave>>1)*64;
  int ar = lane&15, kb = (lane>>4)*8;
  f32x4 acc[G][2][4] = {};

  for (int kc=0; kc<ksteps; ++kc){
    __syncthreads();
    {
      int row = tid>>2, seg = tid&3;
      int gm = m0 + row;
      short8 v = {0,0,0,0,0,0,0,0};
      if (gm < M){
        const unsigned short* p = (kc < kc1)
          ? (A1 + (size_t)gm*lda1 + kc*32 + seg*8)
          : (A2 + (size_t)gm*lda2 + (kc-kc1)*32 + seg*8);
        v = *reinterpret_cast<const short8*>(p);
      }
      *reinterpret_cast<short8*>(&As[row*40 + seg*8]) = v;
    }
    #pragma unroll
    for (int rep=0; rep<2*G; ++rep){
      int u = tid + rep*256;
      int row = u>>2, seg = u&3;        // row in [0, G*128)
      int g = row>>7, rr2 = row&127;
      const unsigned short* q = WN + (size_t)(g*256 + n0r + rr2)*KN + kc*32 + seg*8;
      *reinterpret_cast<short8*>(&Bs[row*40 + seg*8]) = *reinterpret_cast<const short8*>(q);
    }
    __syncthreads();
    short8 af[2];
    #pragma unroll
    for (int mi=0; mi<2; ++mi)
      af[mi] = *reinterpret_cast<const short8*>(&As[(wm + mi*16 + ar)*40 + kb]);
    #pragma unroll
    for (int g=0; g<G; ++g){
      #pragma unroll
      for (int nj=0; nj<4; ++nj){
        short8 bfr = *reinterpret_cast<const short8*>(&Bs[(g*128 + wn + nj*16 + ar)*40 + kb]);
        #pragma unroll
        for (int mi=0; mi<2; ++mi)
          acc[g][mi][nj] = __builtin_amdgcn_mfma_f32_16x16x32_bf16(af[mi], bfr, acc[g][mi][nj], 0,0,0);
      }
    }
  }

  int rr = (lane>>4)*4, cc = lane&15;
  #pragma unroll
  for (int mi=0; mi<2; ++mi){
    #pragma unroll
    for (int r=0; r<4; ++r){
      int p = m0 + wm + mi*16 + rr + r;
      if (p < M){
        #pragma unroll
        for (int nj=0; nj<4; ++nj){
          int i = n0r + wn + nj*16 + cc;
          float ig = sigm (acc[0][mi][nj][r] + bias[i]);
          float og = sigm (acc[1][mi][nj][r] + bias[256+i]);
          float uu = ftanh(acc[2][mi][nj][r] + bias[512+i]);
          float ccv = ig*uu;
          if (G == 4){
            float fxv = acc[3][mi][nj][r] + bias[768+i];
            float fc = 0.f;
            #pragma unroll
            for (int c=0;c<4;c++){
              int k = 4*p + c;
              fc += sigm(bf2f(ybuf[(size_t)k*512 + 256 + i]) + fxv)
                    * c_child[(size_t)k*H + i];
            }
            ccv += fc;
          }
          float hh = og*ftanh(ccv);
          c_out[(size_t)p*H + i] = ccv;
          h_out[(size_t)p*H + i] = f2bf(hh);
          if (G == 4 && p == rootrow) hroot[i] = hh;
        }
      }
    }
  }
}

// ---------------- per-level child GEMM: [e2h|fh] per type-block --------------
__launch_bounds__(256)
__global__ void k_gemm_ch(const unsigned short* __restrict__ hb, const int* __restrict__ edge_type,
                          const int* __restrict__ perm, const int* __restrict__ ptot,
                          const unsigned short* __restrict__ WE,
                          unsigned short* __restrict__ ybuf, int lvl)
{
  int childbase = g_offs[lvl-1];
  int nodebase  = g_offs[lvl];
  int permbase  = childbase + (lvl-1)*PERMPAD;
  int j0 = blockIdx.x*32;
  if (j0 >= ptot[lvl-1]) return;

  __shared__ __align__(16) unsigned short As[32*40];
  __shared__ __align__(16) unsigned short Bs[512*40];
  __shared__ int ks[32];
  int tid = threadIdx.x, lane = tid&63, wave = tid>>6;
  if (tid < 32) ks[tid] = perm[permbase + j0 + tid];
  __syncthreads();
  int k0 = ks[0];
  int e = edge_type[(nodebase + (k0>>2))*4 + (k0&3)];
  const unsigned short* WEe = WE + (size_t)e*512*256;
  f32x4 acc[2][8] = {};
  int ar = lane&15, kb = (lane>>4)*8;

  for (int kc=0; kc<8; ++kc){
    __syncthreads();
    if (tid < 128){
      int row = tid>>2, seg = tid&3;
      int k = ks[row];
      short8 v = {0,0,0,0,0,0,0,0};
      if (k >= 0)
        v = *reinterpret_cast<const short8*>(hb + (size_t)(childbase+k)*H + kc*32 + seg*8);
      *reinterpret_cast<short8*>(&As[row*40 + seg*8]) = v;
    }
    #pragma unroll
    for (int rep=0; rep<8; ++rep){
      int u = tid + rep*256;
      int row = u>>2, seg = u&3;
      *reinterpret_cast<short8*>(&Bs[row*40 + seg*8]) =
        *reinterpret_cast<const short8*>(WEe + (size_t)row*256 + kc*32 + seg*8);
    }
    __syncthreads();
    short8 af[2], bfr[8];
    af[0] = *reinterpret_cast<const short8*>(&As[(ar)*40 + kb]);
    af[1] = *reinterpret_cast<const short8*>(&As[(16+ar)*40 + kb]);
    #pragma unroll
    for (int j=0;j<8;j++)
      bfr[j] = *reinterpret_cast<const short8*>(&Bs[(wave*128 + j*16 + ar)*40 + kb]);
    #pragma unroll
    for (int i=0;i<2;i++)
      #pragma unroll
      for (int j=0;j<8;j++)
        acc[i][j] = __builtin_amdgcn_mfma_f32_16x16x32_bf16(af[i], bfr[j], acc[i][j], 0,0,0);
  }

  int rr = (lane>>4)*4, cc = lane&15;
  #pragma unroll
  for (int i=0;i<2;i++){
    #pragma unroll
    for (int r=0;r<4;r++){
      int ml = i*16 + rr + r;
      int k = ks[ml];
      if (k >= 0){
        #pragma unroll
        for (int j=0;j<8;j++){
          int n = wave*128 + j*16 + cc;
          ybuf[(size_t)k*512 + n] = f2bf(acc[i][j][r]);
        }
      }
    }
  }
}

// ---------------- sum 4 children e2h outputs -> hsumb (bf16) -----------------
__global__ void k_reduce4(const unsigned short* __restrict__ ybuf,
                          unsigned short* __restrict__ hsumb, int m)
{
  int u = blockIdx.x*blockDim.x + threadIdx.x;
  if (u >= m*32) return;
  int p = u>>5, i0 = (u&31)*8;
  float s[8] = {0,0,0,0,0,0,0,0};
  #pragma unroll
  for (int c=0;c<4;c++){
    short8 v = *reinterpret_cast<const short8*>(ybuf + (size_t)(4*p+c)*512 + i0);
    #pragma unroll
    for (int j=0;j<8;j++) s[j] += bf2f((unsigned short)v[j]);
  }
  short8 o;
  #pragma unroll
  for (int j=0;j<8;j++) o[j] = (short)f2bf(s[j]);
  *reinterpret_cast<short8*>(hsumb + (size_t)p*H + i0) = o;
}

__global__ void k_out(const float* __restrict__ c_all, const float* __restrict__ hroot,
                      float* __restrict__ out)
{
  int i = threadIdx.x;
  out[i]     = c_all[(size_t)(NTOT-1)*H + i];
  out[256+i] = hroot[i];
}

// -----------------------------------------------------------------------------
extern "C" void kernel_launch(void* const* d_in, const int* in_sizes, int n_in,
                              void* d_out, int out_size, void* d_ws, size_t ws_size,
                              hipStream_t stream)
{
  const float* x        = (const float*)d_in[0];
  const int*   edge_type= (const int*)d_in[2];
  const float* e2h_w    = (const float*)d_in[5];
  const float* ioux_w   = (const float*)d_in[6];
  const float* ioux_b   = (const float*)d_in[7];
  const float* iouh_w   = (const float*)d_in[8];
  const float* iouh_b   = (const float*)d_in[9];
  const float* fx_w     = (const float*)d_in[10];
  const float* fx_b     = (const float*)d_in[11];
  const float* fh_w     = (const float*)d_in[12];
  const float* fh_b     = (const float*)d_in[13];
  float* out = (float*)d_out;

  char* ws = (char*)d_ws;
  size_t o = 0;
  auto alloc = [&](size_t bytes){ size_t r = o; o += (bytes + 255) & ~(size_t)255; return r; };
  size_t off_xb    = alloc((size_t)NROWS*KX*2);        // 56 MB bf16 x (padded)
  size_t off_hb    = alloc((size_t)NROWS*H*2);         // 44.8 MB bf16 h
  size_t off_c     = alloc((size_t)NTOT*H*4);          // 89.5 MB fp32 c
  size_t off_WN    = alloc((size_t)1024*KN*2);         // 1.2 MB
  size_t off_WE    = alloc((size_t)NE*512*256*2);      // 9.7 MB
  size_t off_bias  = alloc(1024*4);
  size_t off_ybuf  = alloc((size_t)NLEAF*512*2);       // 67 MB
  size_t off_hsumb = alloc((size_t)16384*H*2);         // 8.4 MB
  size_t off_hroot = alloc(256*4);
  size_t off_perm  = alloc((size_t)(NICH + 8*PERMPAD)*4);
  size_t off_bhist = alloc((size_t)HB*NBINS*4);
  size_t off_boff  = alloc((size_t)HB*NBINS*4);
  size_t off_ptot  = alloc(8*4);

  unsigned short* xb    = (unsigned short*)(ws + off_xb);
  unsigned short* hb    = (unsigned short*)(ws + off_hb);
  float*          c_all = (float*)(ws + off_c);
  unsigned short* WN    = (unsigned short*)(ws + off_WN);
  unsigned short* WE    = (unsigned short*)(ws + off_WE);
  float*          bias  = (float*)(ws + off_bias);
  unsigned short* ybuf  = (unsigned short*)(ws + off_ybuf);
  unsigned short* hsumb = (unsigned short*)(ws + off_hsumb);
  float*          hroot = (float*)(ws + off_hroot);
  int* perm  = (int*)(ws + off_perm);
  int* bhist = (int*)(ws + off_bhist);
  int* boff  = (int*)(ws + off_boff);
  int* ptot  = (int*)(ws + off_ptot);

  hipMemsetAsync(perm, 0xFF, (size_t)(NICH + 8*PERMPAD)*4, stream);

  k_convx<<<2048, 256, 0, stream>>>(x, xb);
  k_convw<<<2048, 256, 0, stream>>>(ioux_w, fx_w, iouh_w, fh_w, e2h_w, WN, WE);
  k_bias <<<4, 256, 0, stream>>>(ioux_b, iouh_b, fx_b, fh_b, bias);
  k_hist2   <<<HB, 256, 0, stream>>>(edge_type, bhist);
  k_scan    <<<1, 512, 0, stream>>>(bhist, boff, ptot);
  k_scatter2<<<HB, 256, 0, stream>>>(edge_type, boff, perm);

  // leaves: gates = x @ WN[iou]^T + b -> h,c fused  (M=65536, K=320)
  k_gemm_gates<3><<<dim3(NLEAF/64, 2), 256, 0, stream>>>(
      xb, KX, xb, KX, WN, bias, NLEAF, 10, 10,
      nullptr, nullptr, c_all, hb, nullptr, -1);

  for (int l=1; l<=8; ++l){
    int s    = h_offs[l];
    int m    = h_offs[l+1] - s;
    int childbase = h_offs[l-1];
    int nch  = s - childbase;
    int nblk = (nch + NE*31 + 31)/32;
    k_gemm_ch<<<nblk, 256, 0, stream>>>(hb, edge_type, perm, ptot, WE, ybuf, l);
    k_reduce4<<<(m*32+255)/256, 256, 0, stream>>>(ybuf, hsumb, m);
    // nodes: gates = [x|hsum] @ WN^T + b -> h,c fused  (K=576)
    k_gemm_gates<4><<<dim3((m+63)/64, 2), 256, 0, stream>>>(
        xb + (size_t)s*KX, KX, hsumb, H, WN, bias, m, 18, 10,
        ybuf, c_all + (size_t)childbase*H,
        c_all + (size_t)s*H, hb + (size_t)s*H,
        hroot, (l==8) ? 0 : -1);
  }
  k_out<<<1, 256, 0, stream>>>(c_all, hroot, out);
}